// Round 6
// baseline (155.566 us; speedup 1.0000x reference)
//
#include <hip/hip_runtime.h>
#include <stdint.h>

typedef __bf16 bf16x8 __attribute__((ext_vector_type(8)));
typedef float floatx4 __attribute__((ext_vector_type(4)));
typedef unsigned short u16;
typedef unsigned int u32;

#define CIN   64
#define COUT  128
#define H_    1855
#define KNB   6
#define KTOT  448      // (1+KNB)*CIN
#define NSTEPS 14      // KTOT / 32
#define RS    456      // LDS base row stride (elems); + per-octet skew of 8

static __device__ inline u16 f32_to_bf16(float f) {
    u32 u = __float_as_uint(f);
    u32 r = (u + 0x7FFFu + ((u >> 16) & 1u)) >> 16;
    return (u16)r;
}

// ---- K1: transpose x f32 [bc][h] -> xt3 bf16 [h][bc] ---------------------
__global__ __launch_bounds__(256) void k_transpose(const float* __restrict__ x,
                                                   u16* __restrict__ xt3) {
    __shared__ u16 tile[64][65];
    int h0  = blockIdx.x * 64;
    int bc0 = blockIdx.y * 64;
    int lane = threadIdx.x & 63;
    int rowq = threadIdx.x >> 6;
    int h = h0 + lane;
    bool hv = h < H_;
#pragma unroll
    for (int i = 0; i < 16; ++i) {
        int row = i * 4 + rowq;          // bc within tile
        u16 v = 0;
        if (hv) v = f32_to_bf16(x[(size_t)(bc0 + row) * H_ + h]);
        tile[row][lane] = v;
    }
    __syncthreads();
#pragma unroll
    for (int i = 0; i < 16; ++i) {
        int hr = i * 4 + rowq;           // h within tile
        int hh = h0 + hr;
        if (hh < H_) xt3[(size_t)hh * 4096 + bc0 + lane] = tile[lane][hr];
    }
}

// ---- K2: pack f32 weights -> bf16 wp[o][s*64+c] + per-h inverse counts ---
__global__ __launch_bounds__(256) void k_pack(const float* __restrict__ wc,
                                              const float* __restrict__ wn,
                                              const int* __restrict__ nbr,
                                              u16* __restrict__ wp,
                                              float* __restrict__ cInvG) {
    int tg = blockIdx.x * 256 + threadIdx.x;
    if (tg < H_) {
        int cnt = 1;
#pragma unroll
        for (int j = 0; j < KNB; ++j) cnt += (nbr[tg * KNB + j] >= 0) ? 1 : 0;
        cInvG[tg] = 1.0f / (float)cnt;
    }
    if (tg >= COUT * KTOT) return;
    int o = tg / KTOT;
    int rem = tg - o * KTOT;
    int s = rem >> 6, c = rem & 63;
    float v = (s == 0) ? wc[o * CIN + c]
                       : wn[(o * CIN + c) * KNB + (s - 1)];
    wp[tg] = f32_to_bf16(v);
}

// ---- K3: main gather-GEMM ------------------------------------------------
// grid = 928: boct = blk&7 (XCD pin: 1.9 MB xt3 column slice L2-hot).
// Block: b-octet, 2 h-octet tiles. Tile: M=128 o (A=W in registers, 4 waves
// x 32 rows), N=64 = 8b x 8h (n = bl*8+hl), K=448 = 14 x mfma 16x16x32 bf16.
// Staging gathers coalesced (1 KB contiguous per (hl,s) wave-instr).
// Epilogue: direct f32 stores from acc (C/D layout) — no LDS reuse.
__global__ __launch_bounds__(256, 2) void k_main(const u16* __restrict__ xt3,
                                                 const u16* __restrict__ wp,
                                                 const int* __restrict__ nbr,
                                                 const float* __restrict__ bias,
                                                 const float* __restrict__ cInvG,
                                                 float* __restrict__ out) {
    // X: skewed [n][k]: addr = n*RS + (n>>3)*8 + k. Max 63*456+56+447 = 29231.
    __shared__ __align__(16) u16 X[29248];

    int tid  = threadIdx.x;
    int g    = blockIdx.x;
    int boct = g & 7;
    int T    = g >> 3;            // 0..115 -> tiles {2T, 2T+1}
    int b0   = boct * 8;

    int lane = tid & 63;
    int wave = tid >> 6;
    int col  = lane & 15;
    int quad = lane >> 4;
    int m0w  = wave * 32;
    int bl   = lane >> 3;
    int chunk = lane & 7;

    // A fragments (weights) once per block: A[m=lane&15][k=quad*8+j]
    bf16x8 afrag[2][NSTEPS];
#pragma unroll
    for (int mt = 0; mt < 2; ++mt) {
        int o = m0w + mt * 16 + col;
#pragma unroll
        for (int kk = 0; kk < NSTEPS; ++kk)
            afrag[mt][kk] = *(const bf16x8*)(wp + o * KTOT + kk * 32 + quad * 8);
    }
    float biasv[2][4];
#pragma unroll
    for (int mt = 0; mt < 2; ++mt)
#pragma unroll
        for (int r = 0; r < 4; ++r)
            biasv[mt][r] = bias[m0w + mt * 16 + quad * 4 + r];

#pragma unroll
    for (int tt = 0; tt < 2; ++tt) {
        int t = T * 2 + tt;       // 0..231
        int h0 = t * 8;
        __syncthreads();          // prev tile's B-frag LDS reads done -> X reusable

        // staging: wave handles hl in {2w, 2w+1}, s = 0..6. One coalesced
        // 1-KB load per (hl,s): lane = bl*8+chunk -> base + lane*16B.
#pragma unroll
        for (int i = 0; i < 14; ++i) {
            int hl = wave * 2 + (i < 7 ? 0 : 1);
            int s  = (i < 7) ? i : (i - 7);
            int h  = h0 + hl;
            int src = -1;
            if (h < H_) src = (s == 0) ? h : nbr[h * KNB + (s - 1)];
            uint4 v = make_uint4(0u, 0u, 0u, 0u);
            if (src >= 0)
                v = *(const uint4*)(xt3 + (size_t)src * 4096 + (b0 + bl) * 64 + chunk * 8);
            int n = bl * 8 + hl;
            *(uint4*)(X + n * RS + bl * 8 + s * 64 + chunk * 8) = v;
        }
        __syncthreads();

        floatx4 acc[2][4];
#pragma unroll
        for (int mt = 0; mt < 2; ++mt)
#pragma unroll
            for (int nt = 0; nt < 4; ++nt)
                acc[mt][nt] = (floatx4){0.0f, 0.0f, 0.0f, 0.0f};

        // per-nt lane read bases (skewed layout)
        int rb[4];
#pragma unroll
        for (int nt = 0; nt < 4; ++nt) {
            int n = nt * 16 + col;
            rb[nt] = n * RS + (n >> 3) * 8 + quad * 8;
        }

#pragma unroll
        for (int kk = 0; kk < NSTEPS; ++kk) {
#pragma unroll
            for (int nt = 0; nt < 4; ++nt) {
                bf16x8 bfr = *(const bf16x8*)(X + rb[nt] + kk * 32);
                acc[0][nt] = __builtin_amdgcn_mfma_f32_16x16x32_bf16(
                    afrag[0][kk], bfr, acc[0][nt], 0, 0, 0);
                acc[1][nt] = __builtin_amdgcn_mfma_f32_16x16x32_bf16(
                    afrag[1][kk], bfr, acc[1][nt], 0, 0, 0);
            }
        }

        // epilogue: direct f32 stores. C/D: col=lane&15 -> n, row=quad*4+r -> o.
        int hh = h0 + (col & 7);             // n&7 == col&7 for all nt
        float ic = cInvG[hh < H_ ? hh : 0];
        bool hv = hh < H_;
#pragma unroll
        for (int nt = 0; nt < 4; ++nt) {
            int n = nt * 16 + col;
            size_t rowbase = ((size_t)(b0 + (n >> 3)) * COUT) * H_ + hh;
#pragma unroll
            for (int mt = 0; mt < 2; ++mt)
#pragma unroll
                for (int r = 0; r < 4; ++r) {
                    int o = m0w + mt * 16 + quad * 4 + r;
                    if (hv)
                        out[rowbase + (size_t)o * H_] =
                            acc[mt][nt][r] * ic + biasv[mt][r];
                }
        }
    }
}

extern "C" void kernel_launch(void* const* d_in, const int* in_sizes, int n_in,
                              void* d_out, int out_size, void* d_ws, size_t ws_size,
                              hipStream_t stream) {
    const float* x    = (const float*)d_in[0];   // f32 [64,64,1855]
    const int*   nbr  = (const int*)d_in[1];     // int32 [1855,6]
    const float* wc   = (const float*)d_in[2];   // f32 [128,64]
    const float* wn   = (const float*)d_in[3];   // f32 [128,64,6]
    const float* bias = (const float*)d_in[4];   // f32 [128]

    u16*   xt3   = (u16*)d_ws;                                   // [1855][4096] bf16
    u16*   wp    = (u16*)((char*)d_ws + (size_t)H_ * 4096 * 2);  // [128][448] bf16
    float* cInvG = (float*)((char*)d_ws + (size_t)H_ * 4096 * 2 + (size_t)COUT * KTOT * 2);

    k_pack<<<dim3((COUT * KTOT) / 256), dim3(256), 0, stream>>>(wc, wn, nbr, wp, cInvG);
    k_transpose<<<dim3(29, 64), dim3(256), 0, stream>>>(x, xt3);
    k_main<<<dim3(928), dim3(256), 0, stream>>>(xt3, wp, nbr, bias, cInvG, (float*)d_out);
}

// Round 7
// 153.233 us; speedup vs baseline: 1.0152x; 1.0152x over previous
//
#include <hip/hip_runtime.h>
#include <stdint.h>

typedef __bf16 bf16x8 __attribute__((ext_vector_type(8)));
typedef float floatx4 __attribute__((ext_vector_type(4)));
typedef unsigned int u32x4 __attribute__((ext_vector_type(4)));
typedef unsigned short u16;
typedef unsigned int u32;

#define CIN   64
#define COUT  128
#define H_    1855
#define KNB   6
#define KTOT  448      // (1+KNB)*CIN
#define NSTEPS 14      // KTOT / 32
#define RS    456      // LDS base row stride (elems); + per-octet skew of 8

// Force v into VGPRs and make it unrematerializable (defeats load sinking).
#define PIN4(v) asm volatile("" : "+v"(v))

static __device__ inline u16 f32_to_bf16(float f) {
    u32 u = __float_as_uint(f);
    u32 r = (u + 0x7FFFu + ((u >> 16) & 1u)) >> 16;
    return (u16)r;
}

// ---- K1: transpose x f32 [bc][h] -> xt3 bf16 [h][bc] ---------------------
__global__ __launch_bounds__(256) void k_transpose(const float* __restrict__ x,
                                                   u16* __restrict__ xt3) {
    __shared__ u16 tile[64][65];
    int h0  = blockIdx.x * 64;
    int bc0 = blockIdx.y * 64;
    int lane = threadIdx.x & 63;
    int rowq = threadIdx.x >> 6;
    int h = h0 + lane;
    bool hv = h < H_;
#pragma unroll
    for (int i = 0; i < 16; ++i) {
        int row = i * 4 + rowq;          // bc within tile
        u16 v = 0;
        if (hv) v = f32_to_bf16(x[(size_t)(bc0 + row) * H_ + h]);
        tile[row][lane] = v;
    }
    __syncthreads();
#pragma unroll
    for (int i = 0; i < 16; ++i) {
        int hr = i * 4 + rowq;           // h within tile
        int hh = h0 + hr;
        if (hh < H_) xt3[(size_t)hh * 4096 + bc0 + lane] = tile[lane][hr];
    }
}

// ---- K2: pack f32 weights -> bf16 wp[o][s*64+c] + per-h inverse counts ---
__global__ __launch_bounds__(256) void k_pack(const float* __restrict__ wc,
                                              const float* __restrict__ wn,
                                              const int* __restrict__ nbr,
                                              u16* __restrict__ wp,
                                              float* __restrict__ cInvG) {
    int tg = blockIdx.x * 256 + threadIdx.x;
    if (tg < H_) {
        int cnt = 1;
#pragma unroll
        for (int j = 0; j < KNB; ++j) cnt += (nbr[tg * KNB + j] >= 0) ? 1 : 0;
        cInvG[tg] = 1.0f / (float)cnt;
    }
    if (tg >= COUT * KTOT) return;
    int o = tg / KTOT;
    int rem = tg - o * KTOT;
    int s = rem >> 6, c = rem & 63;
    float v = (s == 0) ? wc[o * CIN + c]
                       : wn[(o * CIN + c) * KNB + (s - 1)];
    wp[tg] = f32_to_bf16(v);
}

// ---- K3: main gather-GEMM ------------------------------------------------
// grid = 928 = 29 T x 32 b-pairs. bp = blk&31 -> XCD = bp&7 (4 b-pairs =
// 1.9 MB xt3 slice L2-hot per XCD). Block: b-pair, 2 h-tiles of 32 h.
// Tile: M=128 o (A=W pinned in VGPRs, 4 waves x 32 rows), N=64 = 2b x 32h,
// K=448 = 14 x mfma_f32_16x16x32_bf16. Epilogue: LDS C-restage ->
// 128-B-contiguous stores per (b,o).
__global__ __launch_bounds__(256, 2) void k_main(const u16* __restrict__ xt3,
                                                 const u16* __restrict__ wp,
                                                 const int* __restrict__ nbr,
                                                 const float* __restrict__ bias,
                                                 const float* __restrict__ cInvG,
                                                 float* __restrict__ out) {
    // X: skewed [n][k]: elem addr = n*RS + (n>>3)*8 + k. Max 29231 < 29248.
    __shared__ __align__(16) u16 X[29248];

    int tid  = threadIdx.x;
    int g    = blockIdx.x;
    int bp   = g & 31;            // b-pair; XCD = bp&7
    int T    = g >> 5;            // 0..28 -> tiles {2T, 2T+1}
    int b0   = bp * 2;

    int lane = tid & 63;
    int wave = tid >> 6;
    int col  = lane & 15;
    int quad = lane >> 4;         // also h_sub for staging
    int m0w  = wave * 32;
    int blg  = (lane >> 3) & 1;   // staging b-lane
    int chunk = lane & 7;

    // A fragments (weights) once per block: A[m=lane&15][k=quad*8+j]
    u32x4 afrag[2][NSTEPS];
#pragma unroll
    for (int mt = 0; mt < 2; ++mt) {
        int o = m0w + mt * 16 + col;
#pragma unroll
        for (int kk = 0; kk < NSTEPS; ++kk)
            afrag[mt][kk] = *(const u32x4*)(wp + o * KTOT + kk * 32 + quad * 8);
    }
#pragma unroll
    for (int mt = 0; mt < 2; ++mt)
#pragma unroll
        for (int kk = 0; kk < NSTEPS; ++kk)
            PIN4(afrag[mt][kk]);

    float biasv[2][4];
#pragma unroll
    for (int mt = 0; mt < 2; ++mt)
#pragma unroll
        for (int r = 0; r < 4; ++r)
            biasv[mt][r] = bias[m0w + mt * 16 + quad * 4 + r];

#pragma unroll
    for (int tt = 0; tt < 2; ++tt) {
        int t = T * 2 + tt;       // 0..57
        int h0 = t * 32;
        __syncthreads();          // X (incl. epilogue stage) free for reuse

        // staging: per i, one wave-instr = 4 h-rows x (2b x 64c) 256-B
        // contiguous segments from the XCD-hot xt3 slice.
#pragma unroll
        for (int i = 0; i < 14; ++i) {
            int hl = wave * 8 + (i < 7 ? 0 : 4) + quad;   // quad = h_sub 0..3
            int s  = (i < 7) ? i : (i - 7);
            int h  = h0 + hl;
            int src = -1;
            if (h < H_) src = (s == 0) ? h : nbr[h * KNB + (s - 1)];
            u32x4 v = (u32x4){0u, 0u, 0u, 0u};
            if (src >= 0)
                v = *(const u32x4*)(xt3 + (size_t)src * 4096 + (b0 + blg) * 64 + chunk * 8);
            int n = blg * 32 + hl;
            *(u32x4*)(X + n * RS + (n >> 3) * 8 + s * 64 + chunk * 8) = v;
        }
        __syncthreads();

        // epilogue scale factors (load early; tiny, L2-hot)
        int hA = h0 + col, hB = h0 + 16 + col;
        float icA = cInvG[hA < H_ ? hA : 0];
        float icB = cInvG[hB < H_ ? hB : 0];

        floatx4 acc[2][4];
#pragma unroll
        for (int mt = 0; mt < 2; ++mt)
#pragma unroll
            for (int nt = 0; nt < 4; ++nt)
                acc[mt][nt] = (floatx4){0.0f, 0.0f, 0.0f, 0.0f};

        int rb[4];
#pragma unroll
        for (int nt = 0; nt < 4; ++nt) {
            int n = nt * 16 + col;
            rb[nt] = n * RS + (n >> 3) * 8 + quad * 8;
        }

#pragma unroll
        for (int kk = 0; kk < NSTEPS; ++kk) {
            bf16x8 a0 = __builtin_bit_cast(bf16x8, afrag[0][kk]);
            bf16x8 a1 = __builtin_bit_cast(bf16x8, afrag[1][kk]);
#pragma unroll
            for (int nt = 0; nt < 4; ++nt) {
                bf16x8 bfr = *(const bf16x8*)(X + rb[nt] + kk * 32);
                acc[0][nt] = __builtin_amdgcn_mfma_f32_16x16x32_bf16(
                    a0, bfr, acc[0][nt], 0, 0, 0);
                acc[1][nt] = __builtin_amdgcn_mfma_f32_16x16x32_bf16(
                    a1, bfr, acc[1][nt], 0, 0, 0);
            }
        }

        __syncthreads();          // all B-frag reads done -> reuse X as stage

        // stage C in LDS: stage[o][n], pad 66 (quad offsets 8 banks apart,
        // worst 2-way = free). Wave-local rows -> no barrier before readback.
        float* stage = (float*)X;  // 128*66*4 = 33.8 KB < 58.5 KB
#pragma unroll
        for (int mt = 0; mt < 2; ++mt)
#pragma unroll
            for (int nt = 0; nt < 4; ++nt) {
                float ic = (nt & 1) ? icB : icA;
                int n = nt * 16 + col;
#pragma unroll
                for (int r = 0; r < 4; ++r) {
                    int o = m0w + mt * 16 + quad * 4 + r;
                    stage[o * 66 + n] = acc[mt][nt][r] * ic + biasv[mt][r];
                }
            }

        // coalesced stores: lane = bl2*32 + hl2 -> two 128-B segments/instr
        int hl2 = lane & 31, bl2 = lane >> 5;
        int hh = h0 + hl2;
        bool hv = hh < H_;
#pragma unroll
        for (int rr = 0; rr < 32; ++rr) {
            int o = m0w + rr;
            if (hv)
                out[((size_t)(b0 + bl2) * COUT + o) * H_ + hh] = stage[o * 66 + lane];
        }
    }
}

extern "C" void kernel_launch(void* const* d_in, const int* in_sizes, int n_in,
                              void* d_out, int out_size, void* d_ws, size_t ws_size,
                              hipStream_t stream) {
    const float* x    = (const float*)d_in[0];   // f32 [64,64,1855]
    const int*   nbr  = (const int*)d_in[1];     // int32 [1855,6]
    const float* wc   = (const float*)d_in[2];   // f32 [128,64]
    const float* wn   = (const float*)d_in[3];   // f32 [128,64,6]
    const float* bias = (const float*)d_in[4];   // f32 [128]

    u16*   xt3   = (u16*)d_ws;                                   // [1855][4096] bf16
    u16*   wp    = (u16*)((char*)d_ws + (size_t)H_ * 4096 * 2);  // [128][448] bf16
    float* cInvG = (float*)((char*)d_ws + (size_t)H_ * 4096 * 2 + (size_t)COUT * KTOT * 2);

    k_pack<<<dim3((COUT * KTOT) / 256), dim3(256), 0, stream>>>(wc, wn, nbr, wp, cInvG);
    k_transpose<<<dim3(29, 64), dim3(256), 0, stream>>>(x, xt3);
    k_main<<<dim3(928), dim3(256), 0, stream>>>(xt3, wp, nbr, bias, cInvG, (float*)d_out);
}

// Round 8
// 139.067 us; speedup vs baseline: 1.1186x; 1.1019x over previous
//
#include <hip/hip_runtime.h>
#include <stdint.h>

typedef __bf16 bf16x8 __attribute__((ext_vector_type(8)));
typedef float floatx4 __attribute__((ext_vector_type(4)));
typedef unsigned int u32x4 __attribute__((ext_vector_type(4)));
typedef unsigned short u16;
typedef unsigned int u32;

#define CIN   64
#define COUT  128
#define H_    1855
#define KNB   6
#define KTOT  448      // (1+KNB)*CIN
#define NSTEPS 14      // KTOT / 32

// LDS geometry (bytes): piece (hl,s) = 256 B; hl row = 8 s-slots = 2048 B,
// padded +16 -> 2064 so B-frag reads spread all 32 banks. Buffer = 16 hl.
#define HLROW 2064
#define BUFSZ 33024    // > 15*2064 + 1024 + 1024 = 33008
#define STCP  36       // stageC row pad (floats): 144 B

// ws layout (bytes)
#define WP_OFF   ((size_t)H_ * 4096 * 2)
#define CINV_OFF (WP_OFF + (size_t)COUT * KTOT * 2)
#define ZERO_OFF (CINV_OFF + 7424)            // 256-B aligned

#define PIN4(v) asm volatile("" : "+v"(v))

typedef __attribute__((address_space(1))) unsigned int as1_u32;
typedef __attribute__((address_space(3))) unsigned int as3_u32;
static __device__ __forceinline__ void ld16_to_lds(const void* g, void* l) {
    __builtin_amdgcn_global_load_lds((const as1_u32*)g, (as3_u32*)l, 16, 0, 0);
}

static __device__ inline u16 f32_to_bf16(float f) {
    u32 u = __float_as_uint(f);
    u32 r = (u + 0x7FFFu + ((u >> 16) & 1u)) >> 16;
    return (u16)r;
}

// ---- K1: transpose x f32 [bc][h] -> xt3 bf16 [h][bc] ---------------------
__global__ __launch_bounds__(256) void k_transpose(const float* __restrict__ x,
                                                   u16* __restrict__ xt3) {
    __shared__ u16 tile[64][65];
    int h0  = blockIdx.x * 64;
    int bc0 = blockIdx.y * 64;
    int lane = threadIdx.x & 63;
    int rowq = threadIdx.x >> 6;
    int h = h0 + lane;
    bool hv = h < H_;
#pragma unroll
    for (int i = 0; i < 16; ++i) {
        int row = i * 4 + rowq;
        u16 v = 0;
        if (hv) v = f32_to_bf16(x[(size_t)(bc0 + row) * H_ + h]);
        tile[row][lane] = v;
    }
    __syncthreads();
#pragma unroll
    for (int i = 0; i < 16; ++i) {
        int hr = i * 4 + rowq;
        int hh = h0 + hr;
        if (hh < H_) xt3[(size_t)hh * 4096 + bc0 + lane] = tile[lane][hr];
    }
}

// ---- K2: pack weights + inverse counts + zero page -----------------------
__global__ __launch_bounds__(256) void k_pack(const float* __restrict__ wc,
                                              const float* __restrict__ wn,
                                              const int* __restrict__ nbr,
                                              u16* __restrict__ wp,
                                              float* __restrict__ cInvG,
                                              u32* __restrict__ zeroPg) {
    int tg = blockIdx.x * 256 + threadIdx.x;
    if (tg < 64) zeroPg[tg] = 0u;            // 256-B zero page
    if (tg < H_) {
        int cnt = 1;
#pragma unroll
        for (int j = 0; j < KNB; ++j) cnt += (nbr[tg * KNB + j] >= 0) ? 1 : 0;
        cInvG[tg] = 1.0f / (float)cnt;
    }
    if (tg >= COUT * KTOT) return;
    int o = tg / KTOT;
    int rem = tg - o * KTOT;
    int s = rem >> 6, c = rem & 63;
    float v = (s == 0) ? wc[o * CIN + c]
                       : wn[(o * CIN + c) * KNB + (s - 1)];
    wp[tg] = f32_to_bf16(v);
}

// staging: 8 async global_load_lds per wave per tile. Instruction (hlL, sg):
// 64 lanes = 4 s-pieces (s = sg*4 + lane>>4) x 16 chunk-lanes; each piece =
// 2b x 64c = 256 B contiguous global. LDS dest = uniform base + lane*16.
static __device__ __forceinline__ void stage_tile(
    const u16* __restrict__ xt3, const int* __restrict__ nbr,
    const char* __restrict__ zeroPg, char* bufB,
    int h0t, int b0, int wave, int lane) {
    int lane16 = lane & 15;
    int ssub   = lane >> 4;                  // 0..3
    int bl     = lane16 >> 3;
    int chunk  = lane16 & 7;
#pragma unroll
    for (int i = 0; i < 8; ++i) {
        int hlL = i & 3;
        int sg  = i >> 2;
        int hl  = wave * 4 + hlL;            // 0..15, wave-uniform
        int s   = sg * 4 + ssub;             // 0..7 per-lane
        int hh  = h0t + hl;
        int hcl = hh < H_ ? hh : 0;
        int sidx = (s >= 1 && s <= 6) ? (s - 1) : 0;
        int nv  = nbr[hcl * KNB + sidx];
        int src = (s == 0) ? hcl : nv;
        bool valid = (hh < H_) && (s <= 6) && (src >= 0);
        const char* gp = valid
            ? (const char*)(xt3 + (size_t)src * 4096 + (b0 + bl) * 64 + chunk * 8)
            : (zeroPg + lane16 * 16);
        ld16_to_lds(gp, bufB + hl * HLROW + sg * 1024);
    }
}

// ---- K3: main gather-GEMM, async double-buffered pipeline ----------------
// grid = 928 = 29 h-supertiles x 32 b-pairs (XCD = blk&7 -> 8 b's = 1.9 MB
// xt3 slice L2-hot per XCD). Block: 4 tiles of N=32 (2b x 16h), M=128 o
// (A=W in regs, 4 waves x 32 rows), K=448 = 14 x mfma 16x16x32 bf16.
__global__ __launch_bounds__(256, 2) void k_main(const u16* __restrict__ xt3,
                                                 const u16* __restrict__ wp,
                                                 const int* __restrict__ nbr,
                                                 const float* __restrict__ bias,
                                                 const float* __restrict__ cInvG,
                                                 const char* __restrict__ zeroPg,
                                                 float* __restrict__ out) {
    __shared__ __align__(16) char LDS[2 * BUFSZ];

    int tid  = threadIdx.x;
    int g    = blockIdx.x;
    int bp   = g & 31;            // b-pair; XCD = g&7
    int hs   = g >> 5;            // 0..28
    int b0   = bp * 2;
    int h0   = hs * 64;

    int lane = tid & 63;
    int wave = tid >> 6;
    int col  = lane & 15;
    int quad = lane >> 4;
    int m0w  = wave * 32;

    // A fragments (weights): A[m=lane&15][k=quad*8+j], 112 VGPRs, pinned.
    u32x4 afrag[2][NSTEPS];
#pragma unroll
    for (int mt = 0; mt < 2; ++mt) {
        int o = m0w + mt * 16 + col;
#pragma unroll
        for (int kk = 0; kk < NSTEPS; ++kk)
            afrag[mt][kk] = *(const u32x4*)(wp + o * KTOT + kk * 32 + quad * 8);
    }
#pragma unroll
    for (int mt = 0; mt < 2; ++mt)
#pragma unroll
        for (int kk = 0; kk < NSTEPS; ++kk)
            PIN4(afrag[mt][kk]);

    float biasv[2][4];
#pragma unroll
    for (int mt = 0; mt < 2; ++mt)
#pragma unroll
        for (int r = 0; r < 4; ++r)
            biasv[mt][r] = bias[m0w + mt * 16 + quad * 4 + r];

    // B-frag lane base offsets (bytes) into a buffer, per nt. Bank-optimal:
    // (col + quad) mod 8 uniform over 8 16-B groups.
    int rb0 = col * HLROW + quad * 16;
    int rb1 = rb0 + 128;

    stage_tile(xt3, nbr, zeroPg, LDS, h0, b0, wave, lane);   // tile 0 -> buf0

#pragma unroll
    for (int tt = 0; tt < 4; ++tt) {
        int h0t = h0 + tt * 16;
        char* cur = LDS + (tt & 1) * BUFSZ;

        __syncthreads();          // drains async loads: tile tt staged & visible

        if (tt < 3)               // prefetch tile tt+1 into other buffer (async)
            stage_tile(xt3, nbr, zeroPg, LDS + ((tt + 1) & 1) * BUFSZ,
                       h0t + 16, b0, wave, lane);

        floatx4 acc[2][2];
#pragma unroll
        for (int mt = 0; mt < 2; ++mt)
#pragma unroll
            for (int nt = 0; nt < 2; ++nt)
                acc[mt][nt] = (floatx4){0.0f, 0.0f, 0.0f, 0.0f};

#pragma unroll
        for (int kk = 0; kk < NSTEPS; ++kk) {
            int koff = (kk >> 1) * 256 + (kk & 1) * 64;
            bf16x8 bf0 = *(const bf16x8*)(cur + rb0 + koff);
            bf16x8 bf1 = *(const bf16x8*)(cur + rb1 + koff);
            bf16x8 a0 = __builtin_bit_cast(bf16x8, afrag[0][kk]);
            bf16x8 a1 = __builtin_bit_cast(bf16x8, afrag[1][kk]);
            acc[0][0] = __builtin_amdgcn_mfma_f32_16x16x32_bf16(a0, bf0, acc[0][0], 0, 0, 0);
            acc[1][0] = __builtin_amdgcn_mfma_f32_16x16x32_bf16(a1, bf0, acc[1][0], 0, 0, 0);
            acc[0][1] = __builtin_amdgcn_mfma_f32_16x16x32_bf16(a0, bf1, acc[0][1], 0, 0, 0);
            acc[1][1] = __builtin_amdgcn_mfma_f32_16x16x32_bf16(a1, bf1, acc[1][1], 0, 0, 0);
        }

        __syncthreads();          // block-wide B-frag reads of cur done

        // epilogue: stage C in cur (reuse), then 64-B-segment stores.
        // C/D: col -> n-part (h), quad*4+r -> o-part.
        float* stC = (float*)cur;
        int hEp = h0t + col;
        float ic = cInvG[hEp < H_ ? hEp : 0];
#pragma unroll
        for (int mt = 0; mt < 2; ++mt)
#pragma unroll
            for (int nt = 0; nt < 2; ++nt)
#pragma unroll
                for (int r = 0; r < 4; ++r) {
                    int o = m0w + mt * 16 + quad * 4 + r;
                    stC[o * STCP + nt * 16 + col] = acc[mt][nt][r] * ic + biasv[mt][r];
                }
        // wave reads back only rows it wrote -> no barrier needed here
        int n5 = lane & 31, q2 = lane >> 5;
        int colS = n5 & 15, ntS = n5 >> 4;
        int hS = h0t + colS;
        bool hv = hS < H_;
        size_t obase = ((size_t)(b0 + ntS) * COUT) * H_ + hS;
#pragma unroll
        for (int rr = 0; rr < 16; ++rr) {
            int o = m0w + rr * 2 + q2;
            if (hv) out[obase + (size_t)o * H_] = stC[o * STCP + n5];
        }
    }
}

extern "C" void kernel_launch(void* const* d_in, const int* in_sizes, int n_in,
                              void* d_out, int out_size, void* d_ws, size_t ws_size,
                              hipStream_t stream) {
    const float* x    = (const float*)d_in[0];   // f32 [64,64,1855]
    const int*   nbr  = (const int*)d_in[1];     // int32 [1855,6]
    const float* wc   = (const float*)d_in[2];   // f32 [128,64]
    const float* wn   = (const float*)d_in[3];   // f32 [128,64,6]
    const float* bias = (const float*)d_in[4];   // f32 [128]

    u16*   xt3    = (u16*)d_ws;
    u16*   wp     = (u16*)((char*)d_ws + WP_OFF);
    float* cInvG  = (float*)((char*)d_ws + CINV_OFF);
    u32*   zeroPg = (u32*)((char*)d_ws + ZERO_OFF);

    k_pack<<<dim3((COUT * KTOT + 255) / 256), dim3(256), 0, stream>>>(
        wc, wn, nbr, wp, cInvG, zeroPg);
    k_transpose<<<dim3(29, 64), dim3(256), 0, stream>>>(x, xt3);
    k_main<<<dim3(928), dim3(256), 0, stream>>>(
        xt3, wp, nbr, bias, cInvG, (const char*)zeroPg, (float*)d_out);
}